// Round 1
// baseline (139.810 us; speedup 1.0000x reference)
//
#include <hip/hip_runtime.h>

// CRF forward (log-partition), SEQ=512, BATCH=1024, TAGS=32, fp32 in/out.
//
// R10: occupancy push. R9 was latency-bound at 2 blocks/CU (76 KB LDS,
// VALUBusy 47%, MfmaUtil 24%, Occupancy 36%). Changes:
//  1. Stage exp(feats) as packed bf16 PAIRS (dword i = pk(f(i), f(16+i))),
//     16 dwords/row instead of 32+4 f32 -> one ds_read_b128 per step + 8
//     unpack ops. XOR-swizzled stores (dword ^ ((row>>1)&3)<<2) spread the
//     64-lane row-major write across all banks; reads are row-broadcast.
//  2. Replace the 3-level MFMA combine tree (which needed a 32x36 f32 LDS
//     region per wave) with a sequential 8-wave row-vector chain
//     w <- w * P_k (k=7..0): P stays in registers, 16 f32 FMA + 4 shfl per
//     hop, one 32-float LDS buffer. More precise than the bf16 tree.
// LDS 76 KB -> 33.9 KB => 4 blocks/CU (32 waves/CU), launch_bounds(512,8).

constexpr int SEQ = 512, BATCH = 1024, TAGS = 32;
constexpr int NC = 8, L = SEQ / NC;  // 8 chunks x 64 steps
constexpr int RROW = 16;             // packed row stride in dwords (bf16 pairs)

#define LOG2E 1.4426950408889634f
#define LN2   0.6931471805599453f

typedef __attribute__((ext_vector_type(8))) short short8;
typedef __attribute__((ext_vector_type(4))) float float4v;
typedef __attribute__((ext_vector_type(4))) unsigned uint4v;
union Frag8 { unsigned u[4]; short8 v; };

__device__ __forceinline__ unsigned pk_rn(float x, float y) {  // bf16 pack, x->low
  return __builtin_amdgcn_perm(__float_as_uint(y) + 0x8000u,
                               __float_as_uint(x) + 0x8000u, 0x07060302u);
}
__device__ __forceinline__ unsigned pk_tr(float x, float y) {  // trunc pack, x->low
  return __builtin_amdgcn_perm(__float_as_uint(y), __float_as_uint(x), 0x07060302u);
}

extern "C" __global__ void __launch_bounds__(512, 8) crf_fused(
    const float* __restrict__ feats, const float* __restrict__ mask,
    const float* __restrict__ trans, float* __restrict__ out) {
  // per-wave staging: 66 rows (64 + 2 prefetch over-read pad) x 16 dwords,
  // dword i of row t = pk_bf16(exp f_t(i), exp f_t(16+i)), XOR-swizzled.
  __shared__ unsigned gst[NC][66 * RROW];  // 33,792 B
  __shared__ float c2s[NC];
  __shared__ __align__(16) float ws[TAGS];  // chain vector
  __shared__ float c2x;                     // chain renorm exponent accum

  const int wid = __builtin_amdgcn_readfirstlane((int)(threadIdx.x >> 6));
  const int lane = threadIdx.x & 63;
  const int b = blockIdx.x;  // one batch per block
  const int s = lane & 15, q = lane >> 4;
  unsigned* Wp = &gst[wid][0];

  // ---- stage: lane t handles row t of this chunk (+ its mask bit) ----
  unsigned long long mb;
  {
    const float* fro = feats + ((size_t)(wid * L + lane) * BATCH + b) * TAGS;
    float4v fv[8];
#pragma unroll
    for (int i = 0; i < 8; ++i) fv[i] = *(const float4v*)(fro + 4 * i);
    const float mv = mask[(size_t)(wid * L + lane) * BATCH + b];
    mb = __ballot(mv != 0.0f);  // bit t = step t's mask
    unsigned Upk[16];
#pragma unroll
    for (int j = 0; j < 16; ++j) {
      const float lo = __builtin_amdgcn_exp2f(fv[j >> 2][j & 3] * LOG2E);
      const float hi = __builtin_amdgcn_exp2f(fv[4 + (j >> 2)][j & 3] * LOG2E);
      Upk[j] = pk_rn(lo, hi);  // low16 = f(j), high16 = f(16+j)
    }
    // swizzled store: location d holds content dword d ^ swr (involution)
    const int swr = ((lane >> 1) & 3) << 2;
    unsigned* rp = Wp + lane * RROW;
#pragma unroll
    for (int g = 0; g < 16; g += 4) {
      uint4v t;
#pragma unroll
      for (int k2 = 0; k2 < 4; ++k2) t[k2] = Upk[(g ^ swr) + k2];
      *(uint4v*)(rp + g) = t;
    }
  }

  // ---- constants: sigma-permuted E fragments ----
  int sig[8];
#pragma unroll
  for (int i = 0; i < 8; ++i) sig[i] = (i < 4) ? (4 * q + i) : (16 + 4 * q + (i - 4));
  Frag8 e0, e1;
#pragma unroll
  for (int p = 0; p < 4; ++p) {
    e0.u[p] = pk_rn(__builtin_amdgcn_exp2f(trans[s * TAGS + sig[2 * p]] * LOG2E),
                    __builtin_amdgcn_exp2f(trans[s * TAGS + sig[2 * p + 1]] * LOG2E));
    e1.u[p] = pk_rn(__builtin_amdgcn_exp2f(trans[(16 + s) * TAGS + sig[2 * p]] * LOG2E),
                    __builtin_amdgcn_exp2f(trans[(16 + s) * TAGS + sig[2 * p + 1]] * LOG2E));
  }

  // P (f32, D-layout): P_hc[p] = P[h*16+4q+p, c*16+s]. Init identity.
  float4v P00 = {0, 0, 0, 0}, P01 = {0, 0, 0, 0}, P10 = {0, 0, 0, 0}, P11 = {0, 0, 0, 0};
#pragma unroll
  for (int p = 0; p < 4; ++p) {
    float one = (4 * q + p == s) ? 1.f : 0.f;
    P00[p] = one; P11[p] = one;
  }
  Frag8 B0, B1;
  float c2 = 0.f;
  const float4v zerov = {0.f, 0.f, 0.f, 0.f};

#define PACK_B()                                                        \
  { B0.u[0] = pk_tr(P00[0], P00[1]); B0.u[1] = pk_tr(P00[2], P00[3]);   \
    B0.u[2] = pk_tr(P10[0], P10[1]); B0.u[3] = pk_tr(P10[2], P10[3]);   \
    B1.u[0] = pk_tr(P01[0], P01[1]); B1.u[1] = pk_tr(P01[2], P01[3]);   \
    B1.u[2] = pk_tr(P11[0], P11[1]); B1.u[3] = pk_tr(P11[2], P11[3]); }
  PACK_B()

  // read row t: 16B at dwords (4q ^ swr(t)); unroll-8 folds swr to a constant
#define RDU(t) (*(const uint4v*)(Wp + (t) * RROW + ((4 * q) ^ ((((t) >> 1) & 3) << 2))))

  uint4v Ua = RDU(0), Ub = RDU(1);

#pragma unroll 8
  for (int r = 0; r < L; ++r) {
    const uint4v U = (r & 1) ? Ub : Ua;
    // unguarded over-read at r+2 in {64,65}: inside the 66-row pad
    if (r & 1) Ub = RDU(r + 2); else Ua = RDU(r + 2);

    if ((mb >> r) & 1ull) {  // scalar bit-test
      float4v F0, F1;
#pragma unroll
      for (int i = 0; i < 4; ++i) {
        F0[i] = __uint_as_float(U[i] << 16);          // f(4q+i)
        F1[i] = __uint_as_float(U[i] & 0xffff0000u);  // f(16+4q+i)
      }
      float4v D00 = __builtin_amdgcn_mfma_f32_16x16x32_bf16(e0.v, B0.v, zerov, 0, 0, 0);
      float4v D01 = __builtin_amdgcn_mfma_f32_16x16x32_bf16(e0.v, B1.v, zerov, 0, 0, 0);
      float4v D10 = __builtin_amdgcn_mfma_f32_16x16x32_bf16(e1.v, B0.v, zerov, 0, 0, 0);
      float4v D11 = __builtin_amdgcn_mfma_f32_16x16x32_bf16(e1.v, B1.v, zerov, 0, 0, 0);
      P00 = D00 * F0; P01 = D01 * F0;  // rows h0 scaled by F0, h1 by F1
      P10 = D10 * F1; P11 = D11 * F1;
      PACK_B()
    }

    if ((r & 7) == 7) {  // renorm every 8 (growth <= 2^13.7/step; 2^111 < 2^127)
      float4v m4 = __builtin_elementwise_max(__builtin_elementwise_max(P00, P01),
                                             __builtin_elementwise_max(P10, P11));
      float mx = fmaxf(fmaxf(m4[0], m4[1]), fmaxf(m4[2], m4[3]));
      mx = fmaxf(mx, __shfl_xor(mx, 1, 64));
      mx = fmaxf(mx, __shfl_xor(mx, 2, 64));
      mx = fmaxf(mx, __shfl_xor(mx, 4, 64));
      mx = fmaxf(mx, __shfl_xor(mx, 8, 64));
      mx = fmaxf(mx, __shfl_xor(mx, 16, 64));
      mx = fmaxf(mx, __shfl_xor(mx, 32, 64));
      int ex = (int)((__float_as_uint(mx) >> 23) & 0xFFu) - 127;
      float scl = __uint_as_float((unsigned)(127 - ex) << 23);  // exact 2^-ex
      P00 *= scl; P01 *= scl; P10 *= scl; P11 *= scl;
      c2 += (float)ex;
      PACK_B()
    }
  }

  // ---- epilogue: sequential row-vector chain w <- w * P_k, k = 7..0 ----
  // out = LN2 * (sum c2 + chain exps + log2( (E_end^T * P7 * ... * P0)[30] ))
  if (lane == 0) c2s[wid] = c2;
  if (threadIdx.x == 0) c2x = 0.f;
  __syncthreads();

  for (int k = NC - 1; k >= 0; --k) {
    if (wid == k) {
      float4v w0, w1;  // w[4q+p], w[16+4q+p]
      if (k == NC - 1) {
#pragma unroll
        for (int p = 0; p < 4; ++p) {
          w0[p] = __builtin_amdgcn_exp2f(trans[31 * TAGS + 4 * q + p] * LOG2E);
          w1[p] = __builtin_amdgcn_exp2f(trans[31 * TAGS + 16 + 4 * q + p] * LOG2E);
        }
      } else {
        w0 = *(const float4v*)(ws + 4 * q);
        w1 = *(const float4v*)(ws + 16 + 4 * q);
      }
      float ps = 0.f, pt = 0.f;  // partials for cols s and 16+s
#pragma unroll
      for (int p = 0; p < 4; ++p) {
        ps += w0[p] * P00[p] + w1[p] * P10[p];
        pt += w0[p] * P01[p] + w1[p] * P11[p];
      }
      ps += __shfl_xor(ps, 16, 64); ps += __shfl_xor(ps, 32, 64);
      pt += __shfl_xor(pt, 16, 64); pt += __shfl_xor(pt, 32, 64);
      if (k > 0) {
        // renorm w to keep the chain in fp32 range (cheap, 4 shfl)
        float mx = fmaxf(ps, pt);
        mx = fmaxf(mx, __shfl_xor(mx, 1, 64));
        mx = fmaxf(mx, __shfl_xor(mx, 2, 64));
        mx = fmaxf(mx, __shfl_xor(mx, 4, 64));
        mx = fmaxf(mx, __shfl_xor(mx, 8, 64));
        int ex = (int)((__float_as_uint(mx) >> 23) & 0xFFu) - 127;
        float scl = __uint_as_float((unsigned)(127 - ex) << 23);
        ps *= scl; pt *= scl;
        if (lane == 0) c2x += (float)ex;
        if (lane < 16) { ws[lane] = ps; ws[16 + lane] = pt; }
      } else if (lane == 14) {
        // element 30 = col 16+s with s==14 -> pt on lane 14
        float c2t = ((c2s[0] + c2s[1]) + (c2s[2] + c2s[3])) +
                    ((c2s[4] + c2s[5]) + (c2s[6] + c2s[7])) + c2x;
        out[b] = LN2 * (c2t + __builtin_amdgcn_logf(pt));
      }
    }
    __syncthreads();
  }
}

extern "C" void kernel_launch(void* const* d_in, const int* in_sizes, int n_in,
                              void* d_out, int out_size, void* d_ws, size_t ws_size,
                              hipStream_t stream) {
  const float* feats = (const float*)d_in[0];
  const float* mask  = (const float*)d_in[1];
  const float* trans = (const float*)d_in[2];
  float* out = (float*)d_out;
  hipLaunchKernelGGL(crf_fused, dim3(BATCH), dim3(512), 0, stream,
                     feats, mask, trans, out);
}

// Round 2
// 131.196 us; speedup vs baseline: 1.0657x; 1.0657x over previous
//
#include <hip/hip_runtime.h>

// CRF forward (log-partition), SEQ=512, BATCH=1024, TAGS=32, fp32 in/out.
//
// R11: fix R10's spill regression. R10 shrank LDS 76->34 KB (4 blocks/CU
// possible) but __launch_bounds__(512,8) strangled the allocator to 32 VGPR
// -> ~6 MB scratch spills per dispatch (WRITE_SIZE 32->6176 KB), MfmaUtil
// 24->19. R11 keeps the 34 KB layout + register chain epilogue and relaxes
// to __launch_bounds__(512,6): VGPR cap ~85, body needs ~52-56 (R9 measured
// 52), actual usage <=64 lets HW schedule 8 waves/SIMD = 4 blocks/CU.
// Also removes R10's content-XOR "swizzle" (provably a no-op: it permuted
// contents, not store addresses -> changed no bank pattern).

constexpr int SEQ = 512, BATCH = 1024, TAGS = 32;
constexpr int NC = 8, L = SEQ / NC;  // 8 chunks x 64 steps
constexpr int RROW = 16;             // packed row stride in dwords (bf16 pairs)

#define LOG2E 1.4426950408889634f
#define LN2   0.6931471805599453f

typedef __attribute__((ext_vector_type(8))) short short8;
typedef __attribute__((ext_vector_type(4))) float float4v;
typedef __attribute__((ext_vector_type(4))) unsigned uint4v;
union Frag8 { unsigned u[4]; short8 v; };

__device__ __forceinline__ unsigned pk_rn(float x, float y) {  // bf16 pack, x->low
  return __builtin_amdgcn_perm(__float_as_uint(y) + 0x8000u,
                               __float_as_uint(x) + 0x8000u, 0x07060302u);
}
__device__ __forceinline__ unsigned pk_tr(float x, float y) {  // trunc pack, x->low
  return __builtin_amdgcn_perm(__float_as_uint(y), __float_as_uint(x), 0x07060302u);
}

extern "C" __global__ void __launch_bounds__(512, 6) crf_fused(
    const float* __restrict__ feats, const float* __restrict__ mask,
    const float* __restrict__ trans, float* __restrict__ out) {
  // per-wave staging: 66 rows (64 + 2 prefetch over-read pad) x 16 dwords,
  // dword i of row t = pk_bf16(exp f_t(i), exp f_t(16+i)).
  __shared__ unsigned gst[NC][66 * RROW];  // 33,792 B
  __shared__ float c2s[NC];
  __shared__ __align__(16) float ws[TAGS];  // chain vector
  __shared__ float c2x;                     // chain renorm exponent accum

  const int wid = __builtin_amdgcn_readfirstlane((int)(threadIdx.x >> 6));
  const int lane = threadIdx.x & 63;
  const int b = blockIdx.x;  // one batch per block
  const int s = lane & 15, q = lane >> 4;
  unsigned* Wp = &gst[wid][0];

  // ---- stage: lane t handles row t of this chunk (+ its mask bit) ----
  unsigned long long mb;
  {
    const float* fro = feats + ((size_t)(wid * L + lane) * BATCH + b) * TAGS;
    float4v fv[8];
#pragma unroll
    for (int i = 0; i < 8; ++i) fv[i] = *(const float4v*)(fro + 4 * i);
    const float mv = mask[(size_t)(wid * L + lane) * BATCH + b];
    mb = __ballot(mv != 0.0f);  // bit t = step t's mask
    unsigned* rp = Wp + lane * RROW;
#pragma unroll
    for (int g = 0; g < 4; ++g) {
      uint4v t;
#pragma unroll
      for (int k2 = 0; k2 < 4; ++k2) {
        const int j = 4 * g + k2;
        const float lo = __builtin_amdgcn_exp2f(fv[j >> 2][j & 3] * LOG2E);
        const float hi = __builtin_amdgcn_exp2f(fv[4 + (j >> 2)][j & 3] * LOG2E);
        t[k2] = pk_rn(lo, hi);  // low16 = f(j), high16 = f(16+j)
      }
      *(uint4v*)(rp + 4 * g) = t;
    }
  }

  // ---- constants: sigma-permuted E fragments ----
  int sig[8];
#pragma unroll
  for (int i = 0; i < 8; ++i) sig[i] = (i < 4) ? (4 * q + i) : (16 + 4 * q + (i - 4));
  Frag8 e0, e1;
#pragma unroll
  for (int p = 0; p < 4; ++p) {
    e0.u[p] = pk_rn(__builtin_amdgcn_exp2f(trans[s * TAGS + sig[2 * p]] * LOG2E),
                    __builtin_amdgcn_exp2f(trans[s * TAGS + sig[2 * p + 1]] * LOG2E));
    e1.u[p] = pk_rn(__builtin_amdgcn_exp2f(trans[(16 + s) * TAGS + sig[2 * p]] * LOG2E),
                    __builtin_amdgcn_exp2f(trans[(16 + s) * TAGS + sig[2 * p + 1]] * LOG2E));
  }

  // P (f32, D-layout): P_hc[p] = P[h*16+4q+p, c*16+s]. Init identity.
  float4v P00 = {0, 0, 0, 0}, P01 = {0, 0, 0, 0}, P10 = {0, 0, 0, 0}, P11 = {0, 0, 0, 0};
#pragma unroll
  for (int p = 0; p < 4; ++p) {
    float one = (4 * q + p == s) ? 1.f : 0.f;
    P00[p] = one; P11[p] = one;
  }
  Frag8 B0, B1;
  float c2 = 0.f;
  const float4v zerov = {0.f, 0.f, 0.f, 0.f};

#define PACK_B()                                                        \
  { B0.u[0] = pk_tr(P00[0], P00[1]); B0.u[1] = pk_tr(P00[2], P00[3]);   \
    B0.u[2] = pk_tr(P10[0], P10[1]); B0.u[3] = pk_tr(P10[2], P10[3]);   \
    B1.u[0] = pk_tr(P01[0], P01[1]); B1.u[1] = pk_tr(P01[2], P01[3]);   \
    B1.u[2] = pk_tr(P11[0], P11[1]); B1.u[3] = pk_tr(P11[2], P11[3]); }
  PACK_B()

  // read row t: one ds_read_b128; 16 lanes broadcast each address, 4 distinct
  // addresses hit disjoint bank groups -> conflict-free.
#define RDU(t) (*(const uint4v*)(Wp + (t) * RROW + 4 * q))

  uint4v Ua = RDU(0), Ub = RDU(1);

#pragma unroll 8
  for (int r = 0; r < L; ++r) {
    const uint4v U = (r & 1) ? Ub : Ua;
    // unguarded over-read at r+2 in {64,65}: inside the 66-row pad
    if (r & 1) Ub = RDU(r + 2); else Ua = RDU(r + 2);

    if ((mb >> r) & 1ull) {  // scalar bit-test
      float4v F0, F1;
#pragma unroll
      for (int i = 0; i < 4; ++i) {
        F0[i] = __uint_as_float(U[i] << 16);          // f(4q+i)
        F1[i] = __uint_as_float(U[i] & 0xffff0000u);  // f(16+4q+i)
      }
      float4v D00 = __builtin_amdgcn_mfma_f32_16x16x32_bf16(e0.v, B0.v, zerov, 0, 0, 0);
      float4v D01 = __builtin_amdgcn_mfma_f32_16x16x32_bf16(e0.v, B1.v, zerov, 0, 0, 0);
      float4v D10 = __builtin_amdgcn_mfma_f32_16x16x32_bf16(e1.v, B0.v, zerov, 0, 0, 0);
      float4v D11 = __builtin_amdgcn_mfma_f32_16x16x32_bf16(e1.v, B1.v, zerov, 0, 0, 0);
      P00 = D00 * F0; P01 = D01 * F0;  // rows h0 scaled by F0, h1 by F1
      P10 = D10 * F1; P11 = D11 * F1;
      PACK_B()
    }

    if ((r & 7) == 7) {  // renorm every 8 (growth <= 2^13.7/step; 2^111 < 2^127)
      float4v m4 = __builtin_elementwise_max(__builtin_elementwise_max(P00, P01),
                                             __builtin_elementwise_max(P10, P11));
      float mx = fmaxf(fmaxf(m4[0], m4[1]), fmaxf(m4[2], m4[3]));
      mx = fmaxf(mx, __shfl_xor(mx, 1, 64));
      mx = fmaxf(mx, __shfl_xor(mx, 2, 64));
      mx = fmaxf(mx, __shfl_xor(mx, 4, 64));
      mx = fmaxf(mx, __shfl_xor(mx, 8, 64));
      mx = fmaxf(mx, __shfl_xor(mx, 16, 64));
      mx = fmaxf(mx, __shfl_xor(mx, 32, 64));
      int ex = (int)((__float_as_uint(mx) >> 23) & 0xFFu) - 127;
      float scl = __uint_as_float((unsigned)(127 - ex) << 23);  // exact 2^-ex
      P00 *= scl; P01 *= scl; P10 *= scl; P11 *= scl;
      c2 += (float)ex;
      PACK_B()
    }
  }

  // ---- epilogue: sequential row-vector chain w <- w * P_k, k = 7..0 ----
  // out = LN2 * (sum c2 + chain exps + log2( (E_end^T * P7 * ... * P0)[30] ))
  if (lane == 0) c2s[wid] = c2;
  if (threadIdx.x == 0) c2x = 0.f;
  __syncthreads();

  for (int k = NC - 1; k >= 0; --k) {
    if (wid == k) {
      float4v w0, w1;  // w[4q+p], w[16+4q+p]
      if (k == NC - 1) {
#pragma unroll
        for (int p = 0; p < 4; ++p) {
          w0[p] = __builtin_amdgcn_exp2f(trans[31 * TAGS + 4 * q + p] * LOG2E);
          w1[p] = __builtin_amdgcn_exp2f(trans[31 * TAGS + 16 + 4 * q + p] * LOG2E);
        }
      } else {
        w0 = *(const float4v*)(ws + 4 * q);
        w1 = *(const float4v*)(ws + 16 + 4 * q);
      }
      float ps = 0.f, pt = 0.f;  // partials for cols s and 16+s
#pragma unroll
      for (int p = 0; p < 4; ++p) {
        ps += w0[p] * P00[p] + w1[p] * P10[p];
        pt += w0[p] * P01[p] + w1[p] * P11[p];
      }
      ps += __shfl_xor(ps, 16, 64); ps += __shfl_xor(ps, 32, 64);
      pt += __shfl_xor(pt, 16, 64); pt += __shfl_xor(pt, 32, 64);
      if (k > 0) {
        // renorm w to keep the chain in fp32 range (cheap, 4 shfl)
        float mx = fmaxf(ps, pt);
        mx = fmaxf(mx, __shfl_xor(mx, 1, 64));
        mx = fmaxf(mx, __shfl_xor(mx, 2, 64));
        mx = fmaxf(mx, __shfl_xor(mx, 4, 64));
        mx = fmaxf(mx, __shfl_xor(mx, 8, 64));
        int ex = (int)((__float_as_uint(mx) >> 23) & 0xFFu) - 127;
        float scl = __uint_as_float((unsigned)(127 - ex) << 23);
        ps *= scl; pt *= scl;
        if (lane == 0) c2x += (float)ex;
        if (lane < 16) { ws[lane] = ps; ws[16 + lane] = pt; }
      } else if (lane == 14) {
        // element 30 = col 16+s with s==14 -> pt on lane 14
        float c2t = ((c2s[0] + c2s[1]) + (c2s[2] + c2s[3])) +
                    ((c2s[4] + c2s[5]) + (c2s[6] + c2s[7])) + c2x;
        out[b] = LN2 * (c2t + __builtin_amdgcn_logf(pt));
      }
    }
    __syncthreads();
  }
}

extern "C" void kernel_launch(void* const* d_in, const int* in_sizes, int n_in,
                              void* d_out, int out_size, void* d_ws, size_t ws_size,
                              hipStream_t stream) {
  const float* feats = (const float*)d_in[0];
  const float* mask  = (const float*)d_in[1];
  const float* trans = (const float*)d_in[2];
  float* out = (float*)d_out;
  hipLaunchKernelGGL(crf_fused, dim3(BATCH), dim3(512), 0, stream,
                     feats, mask, trans, out);
}